// Round 8
// baseline (307.103 us; speedup 1.0000x reference)
//
#include <hip/hip_runtime.h>
#include <cmath>

// SpikingLayer forward — static-schedule producer/consumer, DENSE gold r-scan.
//
// vmem[t] = sum_{k<100} (am^k - as^k) x[t-k] (exact truncated-FIR via dual
// 1st-order f64 recurrences; time-chunked, 288-step zero-history warmup:
// mathematically exact after 100 steps, rounding-only deviation ~1e-15 —
// proven flip-free in round 5). The nonlinear refractory scan is NEVER
// chunked: wave 3 runs it sequentially per neuron in f64 with the exact
// round-5 op order (absmax 0.0).
//
// BISECTION NOTE (round 8): round 7 = this static schedule + sparse consumer
// + alpha-power table -> absmax 1.0. Round 5 = dynamic flags + THIS dense
// consumer -> absmax 0.0. This round: static schedule + dense consumer.
// Pass => sparse-path was the bug (and is unnecessary: dense chain ~12us <<
// ~40us HBM floor). Fail => static schedule is broken.
//
// Static lockstep: stored tile gt is produced exactly at iteration it==gt,
// consumed at it==gt+1. RING=2: writer slot it&1, reader slot (it-1)&1 —
// disjoint, strictly barrier-separated. No atomics, no polling.
//   P0 (wave 0): tiles 0..16  (it 0..16,  no warmup,    t0=0)
//   P1 (wave 1): tiles 17..24 (it 8..24,  9 warm tiles, t0=256)
//   P2 (wave 2): tiles 25..31 (it 16..31, 9 warm tiles, t0=512)
//   C  (wave 3): consumes gt=it-1, flushes coalesced output.
// LDS 43.0 KB -> 3 WG/CU (12 waves/CU).

#define T_LEN  1024
#define NT     32
#define VROWW  33                          // doubles per vmem row (264 B)
#define VSLOTD (64 * VROWW)                // 2112 doubles per ring slot
#define OROWW  36                          // floats per out-staging row
#define LDS_OB  (2 * VSLOTD * 8)           // 33792
#define LDS_TOT (LDS_OB + 64 * OROWW * 4)  // 43008 B

__global__ __launch_bounds__(256, 3)
void spiking_fwd(const float* __restrict__ x, const float* __restrict__ rk,
                 float* __restrict__ out,
                 double a_m, double a_s, double am100, double as100)
{
    __shared__ __align__(16) unsigned char lds[LDS_TOT];
    const int tid = threadIdx.x, wid = tid >> 6, lane = tid & 63;
    const int n0 = blockIdx.x * 64;

    // role parameters (producers)
    int pstart = 0, ptot = 0, pwarm = 0, pt0 = 0;
    if (wid == 0) { pstart = 0;  ptot = 17; pwarm = 0; pt0 = 0;   }
    if (wid == 1) { pstart = 8;  ptot = 17; pwarm = 9; pt0 = 256; }
    if (wid == 2) { pstart = 16; ptot = 16; pwarm = 9; pt0 = 512; }

    // consumer state
    double r = 0.0, alpha = 0.0;
    if (wid == 3) alpha = (double)rk[1] / (double)rk[0];

    // producer state
    double s_m = 0.0, s_s = 0.0;
    unsigned b0 = 0, b1 = 0, b2 = 0, b3 = 0;   // bit FIFO: tiles li-4..li-1
    float cur[32], nxt[32];
    const float* xrow = nullptr;
    if (wid < 3) {
        xrow = x + (size_t)(n0 + lane) * T_LEN + pt0;
        #pragma unroll
        for (int j = 0; j < 8; ++j) {
            float4 t = *(const float4*)(xrow + j * 4);
            cur[4*j+0]=t.x; cur[4*j+1]=t.y; cur[4*j+2]=t.z; cur[4*j+3]=t.w;
        }
    }

    float* const og = out + (size_t)n0 * T_LEN;
    float* const ob = (float*)(lds + LDS_OB);
    const int colq = lane & 7, rowq = lane >> 3;

    for (int it = 0; it <= NT; ++it) {
        if (wid < 3) {
            const int li = it - pstart;
            if (li >= 0 && li < ptot) {
                if (li + 1 < ptot) {               // prefetch next tile
                    #pragma unroll
                    for (int j = 0; j < 8; ++j) {
                        float4 t = *(const float4*)(xrow + (li+1)*32 + j*4);
                        nxt[4*j+0]=t.x; nxt[4*j+1]=t.y; nxt[4*j+2]=t.z; nxt[4*j+3]=t.w;
                    }
                }
                // step t=t0+li*32+k needs x[t-100]: k<4 -> tile li-4 bit 28+k,
                // k>=4 -> tile li-3 bit k-4.
                const unsigned wmask = (b0 >> 28) | (b1 << 4);
                unsigned bcur = 0;
                if (li >= pwarm) {
                    // stored tile: gt = pt0/32 + li == it by construction
                    double* vrow = (double*)lds
                                 + (size_t)(it & 1) * VSLOTD + (size_t)lane * VROWW;
                    #pragma unroll
                    for (int k = 0; k < 32; ++k) {
                        const float  xf = cur[k];
                        const double xc = (double)xf;
                        const unsigned bd = (wmask >> k) & 1u;
                        s_m = fma(a_m, s_m, xc - (bd ? am100 : 0.0));
                        s_s = fma(a_s, s_s, xc - (bd ? as100 : 0.0));
                        vrow[k] = s_m - s_s;
                        if (xf != 0.0f) bcur |= (1u << k);
                    }
                } else {                            // warmup tile
                    #pragma unroll
                    for (int k = 0; k < 32; ++k) {
                        const float  xf = cur[k];
                        const double xc = (double)xf;
                        const unsigned bd = (wmask >> k) & 1u;
                        s_m = fma(a_m, s_m, xc - (bd ? am100 : 0.0));
                        s_s = fma(a_s, s_s, xc - (bd ? as100 : 0.0));
                        if (xf != 0.0f) bcur |= (1u << k);
                    }
                }
                b0 = b1; b1 = b2; b2 = b3; b3 = bcur;
                #pragma unroll
                for (int i2 = 0; i2 < 32; ++i2) cur[i2] = nxt[i2];
            }
        } else {
            const int gt = it - 1;
            if (gt >= 0) {
                const int slot = gt & 1;
                const double* vrow = (const double*)lds
                                   + (size_t)slot * VSLOTD + (size_t)lane * VROWW;
                double vm[32];
                #pragma unroll
                for (int k = 0; k < 32; ++k)        // hoisted LDS reads
                    vm[k] = vrow[k];

                float* orow = ob + lane * OROWW;
                #pragma unroll
                for (int k = 0; k < 32; ++k) {      // gold scan, round-5 op order
                    double v = vm[k] - r;
                    double n = fmax(floor(v), 0.0);
                    r = (r + n) * alpha;
                    orow[k] = (float)n;
                }

                #pragma unroll
                for (int j = 0; j < 8; ++j) {       // coalesced flush
                    const int nn = rowq + 8 * j;
                    float4 t = *(const float4*)(ob + nn * OROWW + colq * 4);
                    *(float4*)(og + (size_t)nn * T_LEN + gt * 32 + colq * 4) = t;
                }
            }
        }
        __syncthreads();
    }
}

extern "C" void kernel_launch(void* const* d_in, const int* in_sizes, int n_in,
                              void* d_out, int out_size, void* d_ws, size_t ws_size,
                              hipStream_t stream)
{
    const float* x  = (const float*)d_in[0];   // binary_input (1,32,1024,1024)
    const float* rk = (const float*)d_in[2];   // ref_kernel (100,)
    float* out = (float*)d_out;                // spikes (32,1024,1024) f32

    const int neurons = in_sizes[0] / T_LEN;   // 32768

    const double a_m   = std::exp(-0.1);       // exp(-dt/tau_mem)
    const double a_s   = std::exp(-0.2);       // exp(-dt/tau_syn)
    const double am100 = std::exp(-10.0);
    const double as100 = std::exp(-20.0);

    dim3 grid(neurons / 64), block(256);
    hipLaunchKernelGGL(spiking_fwd, grid, block, 0, stream,
                       x, rk, out, a_m, a_s, am100, as100);
}

// Round 9
// 141.581 us; speedup vs baseline: 2.1691x; 2.1691x over previous
//
#include <hip/hip_runtime.h>
#include <cmath>

// SpikingLayer forward — static-schedule producer/consumer, dense gold r-scan.
//
// vmem[t] = sum_{k<100} (am^k - as^k) x[t-k] (exact truncated-FIR via dual
// 1st-order f64 recurrences; time-chunked, 288-step zero-history warmup =
// mathematically exact after 100 steps). The nonlinear refractory scan is
// NEVER chunked: wave 3 runs it sequentially per neuron in f64, round-5 op
// order. Round 8 proved this structure correct (absmax 0.0).
//
// ROUND-9 DELTAS (round 8 was correct but 307us due to SCRATCH SPILL:
// VGPR_Count=84 + WRITE_SIZE=625MB = cur/nxt/vm arrays spilled under the
// __launch_bounds__(256,3) cap):
//   1. __launch_bounds__(256,2): VGPR cap 256 -> arrays stay in registers.
//   2. Consumer reads vmem in 2 chunks of 16 (halves its array pressure).
//   3. vmem rows XOR-swizzled (k ^ (lane>>4)&3, BOTH store and read):
//      removes the structural 4-way b64 bank conflict at 66-word stride.
//
// Static lockstep: stored tile gt is produced exactly at iteration it==gt,
// consumed at it==gt+1. RING=2: writer slot it&1, reader slot (it-1)&1 —
// disjoint, strictly barrier-separated. No atomics, no polling.
//   P0 (wave 0): tiles 0..16  (it 0..16,  no warmup,    t0=0)
//   P1 (wave 1): tiles 17..24 (it 8..24,  9 warm tiles, t0=256)
//   P2 (wave 2): tiles 25..31 (it 16..31, 9 warm tiles, t0=512)
//   C  (wave 3): consumes gt=it-1, flushes coalesced output.
// LDS 43.0 KB.

#define T_LEN  1024
#define NT     32
#define VROWW  33                          // doubles per vmem row (264 B)
#define VSLOTD (64 * VROWW)                // 2112 doubles per ring slot
#define OROWW  36                          // floats per out-staging row
#define LDS_OB  (2 * VSLOTD * 8)           // 33792
#define LDS_TOT (LDS_OB + 64 * OROWW * 4)  // 43008 B

__global__ __launch_bounds__(256, 2)
void spiking_fwd(const float* __restrict__ x, const float* __restrict__ rk,
                 float* __restrict__ out,
                 double a_m, double a_s, double am100, double as100)
{
    __shared__ __align__(16) unsigned char lds[LDS_TOT];
    const int tid = threadIdx.x, wid = tid >> 6, lane = tid & 63;
    const int n0 = blockIdx.x * 64;
    const unsigned vsw = (lane >> 4) & 3;   // vmem-row bank swizzle

    // role parameters (producers)
    int pstart = 0, ptot = 0, pwarm = 0, pt0 = 0;
    if (wid == 0) { pstart = 0;  ptot = 17; pwarm = 0; pt0 = 0;   }
    if (wid == 1) { pstart = 8;  ptot = 17; pwarm = 9; pt0 = 256; }
    if (wid == 2) { pstart = 16; ptot = 16; pwarm = 9; pt0 = 512; }

    // consumer state
    double r = 0.0, alpha = 0.0;
    if (wid == 3) alpha = (double)rk[1] / (double)rk[0];

    // producer state
    double s_m = 0.0, s_s = 0.0;
    unsigned b0 = 0, b1 = 0, b2 = 0, b3 = 0;   // bit FIFO: tiles li-4..li-1
    float cur[32], nxt[32];
    const float* xrow = nullptr;
    if (wid < 3) {
        xrow = x + (size_t)(n0 + lane) * T_LEN + pt0;
        #pragma unroll
        for (int j = 0; j < 8; ++j) {
            float4 t = *(const float4*)(xrow + j * 4);
            cur[4*j+0]=t.x; cur[4*j+1]=t.y; cur[4*j+2]=t.z; cur[4*j+3]=t.w;
        }
    }

    float* const og = out + (size_t)n0 * T_LEN;
    float* const ob = (float*)(lds + LDS_OB);
    const int colq = lane & 7, rowq = lane >> 3;

    for (int it = 0; it <= NT; ++it) {
        if (wid < 3) {
            const int li = it - pstart;
            if (li >= 0 && li < ptot) {
                if (li + 1 < ptot) {               // prefetch next tile
                    #pragma unroll
                    for (int j = 0; j < 8; ++j) {
                        float4 t = *(const float4*)(xrow + (li+1)*32 + j*4);
                        nxt[4*j+0]=t.x; nxt[4*j+1]=t.y; nxt[4*j+2]=t.z; nxt[4*j+3]=t.w;
                    }
                }
                // step t=t0+li*32+k needs x[t-100]: k<4 -> tile li-4 bit 28+k,
                // k>=4 -> tile li-3 bit k-4.
                const unsigned wmask = (b0 >> 28) | (b1 << 4);
                unsigned bcur = 0;
                if (li >= pwarm) {
                    // stored tile: gt = pt0/32 + li == it by construction
                    double* vrow = (double*)lds
                                 + (size_t)(it & 1) * VSLOTD + (size_t)lane * VROWW;
                    #pragma unroll
                    for (int k = 0; k < 32; ++k) {
                        const float  xf = cur[k];
                        const double xc = (double)xf;
                        const unsigned bd = (wmask >> k) & 1u;
                        s_m = fma(a_m, s_m, xc - (bd ? am100 : 0.0));
                        s_s = fma(a_s, s_s, xc - (bd ? as100 : 0.0));
                        vrow[k ^ vsw] = s_m - s_s;        // swizzled store
                        if (xf != 0.0f) bcur |= (1u << k);
                    }
                } else {                            // warmup tile
                    #pragma unroll
                    for (int k = 0; k < 32; ++k) {
                        const float  xf = cur[k];
                        const double xc = (double)xf;
                        const unsigned bd = (wmask >> k) & 1u;
                        s_m = fma(a_m, s_m, xc - (bd ? am100 : 0.0));
                        s_s = fma(a_s, s_s, xc - (bd ? as100 : 0.0));
                        if (xf != 0.0f) bcur |= (1u << k);
                    }
                }
                b0 = b1; b1 = b2; b2 = b3; b3 = bcur;
                #pragma unroll
                for (int i2 = 0; i2 < 32; ++i2) cur[i2] = nxt[i2];
            }
        } else {
            const int gt = it - 1;
            if (gt >= 0) {
                const int slot = gt & 1;
                const double* vrow = (const double*)lds
                                   + (size_t)slot * VSLOTD + (size_t)lane * VROWW;
                float* orow = ob + lane * OROWW;

                #pragma unroll
                for (int h = 0; h < 2; ++h) {       // 2 chunks of 16
                    double vmc[16];
                    #pragma unroll
                    for (int k2 = 0; k2 < 16; ++k2)          // swizzled read
                        vmc[k2] = vrow[(h * 16 + k2) ^ vsw];
                    #pragma unroll
                    for (int k2 = 0; k2 < 16; ++k2) {        // gold scan order
                        double v = vmc[k2] - r;
                        double n = fmax(floor(v), 0.0);
                        r = (r + n) * alpha;
                        orow[h * 16 + k2] = (float)n;
                    }
                }

                #pragma unroll
                for (int j = 0; j < 8; ++j) {       // coalesced flush
                    const int nn = rowq + 8 * j;
                    float4 t = *(const float4*)(ob + nn * OROWW + colq * 4);
                    *(float4*)(og + (size_t)nn * T_LEN + gt * 32 + colq * 4) = t;
                }
            }
        }
        __syncthreads();
    }
}

extern "C" void kernel_launch(void* const* d_in, const int* in_sizes, int n_in,
                              void* d_out, int out_size, void* d_ws, size_t ws_size,
                              hipStream_t stream)
{
    const float* x  = (const float*)d_in[0];   // binary_input (1,32,1024,1024)
    const float* rk = (const float*)d_in[2];   // ref_kernel (100,)
    float* out = (float*)d_out;                // spikes (32,1024,1024) f32

    const int neurons = in_sizes[0] / T_LEN;   // 32768

    const double a_m   = std::exp(-0.1);       // exp(-dt/tau_mem)
    const double a_s   = std::exp(-0.2);       // exp(-dt/tau_syn)
    const double am100 = std::exp(-10.0);
    const double as100 = std::exp(-20.0);

    dim3 grid(neurons / 64), block(256);
    hipLaunchKernelGGL(spiking_fwd, grid, block, 0, stream,
                       x, rk, out, a_m, a_s, am100, as100);
}

// Round 10
// 89.145 us; speedup vs baseline: 3.4450x; 1.5882x over previous
//
#include <hip/hip_runtime.h>
#include <cmath>

// SpikingLayer forward — dynamic producer/consumer + dedicated writer wave.
//
// vmem[t] = sum_{k<100} (am^k - as^k) x[t-k] (exact truncated-FIR via dual
// 1st-order f64 recurrences; time-chunked, 288-step zero-history warmup =
// mathematically exact after 100 steps). The nonlinear refractory scan is
// NEVER chunked: wave 3 runs it sequentially per neuron in f64, gold op
// order (rounds 5/8/9 all absmax 0.0 with this math).
//
// Base = round 5 (dynamic flags, 69us). Round-10 deltas attack the consumer
// wave's non-chain overheads (the wall; chain itself ~17us, HBM floor ~36us):
//  1. Consumer vm REGISTER DOUBLE-BUFFER: prefetch tile gt+1's 32 doubles
//     (ds_reads issued before scanning gt) -> LDS latency hides under the
//     ~1300-cyc serial scan. VMRING=3 keeps the producer 2-3 tiles ahead so
//     flag[gt+1] is already set.
//  2. Dedicated WRITER wave (block=320, 5 waves): consumer only scans and
//     writes n into a 2-slot ob ring; wave 4 does the coalesced global
//     flush. Handshake: consumer posts consp (release) after ob write;
//     writer polls consp, flushes, posts wprog; consumer reuses an ob slot
//     only when wprog >= gt-1. Acyclic -> deadlock-free.
//  3. Producer body verbatim round-9 (round-5 gold math + bank swizzle).
// 2560 waves = 10 waves/CU (round 5: 8). LDS 69.3 KB -> 2 WG/CU (grid-limited
// anyway: 512 blocks = 2/CU).

#define T_LEN   1024
#define NT      32
#define VMRING  3
#define VROWW   33                        // doubles per vmem row (264 B)
#define VSLOTD  (64 * VROWW)              // 2112 doubles per ring slot
#define OROWW   36                        // floats per out-staging row
#define OBSLOTW (64 * OROWW)              // 2304 floats per ob slot
#define LDS_OB  (VMRING * VSLOTD * 8)     // 50688
#define LDS_FLG (LDS_OB + 2 * OBSLOTW * 4)// 69120
#define LDS_TOT (LDS_FLG + 34 * 4)        // 69256 B

__global__ __launch_bounds__(320, 2)
void spiking_fwd(const float* __restrict__ x, const float* __restrict__ rk,
                 float* __restrict__ out,
                 double a_m, double a_s, double am100, double as100)
{
    __shared__ __align__(16) unsigned char lds[LDS_TOT];
    int* const flags = (int*)(lds + LDS_FLG);   // [0..31] tile-ready
    int* const consp = flags + NT;              // tiles consumed (scan done)
    int* const wprog = flags + NT + 1;          // tiles flushed to global

    const int tid = threadIdx.x, wid = tid >> 6, lane = tid & 63;
    const int n0 = blockIdx.x * 64;
    const unsigned vsw = (lane >> 4) & 3;       // vmem bank swizzle (r9-proven)

    if (tid < 34) flags[tid] = 0;
    __syncthreads();

    float* const og = out + (size_t)n0 * T_LEN;
    float* const ob = (float*)(lds + LDS_OB);
    const int colq = lane & 7, rowq = lane >> 3;

    if (wid < 3) {
        // ===================== producer (gold math) =====================
        // chunks [0,544) [544,800) [800,1024), warmup 288 for P1/P2
        int pwarm = 0, ptot = 0, pt0 = 0, gt0 = 0;
        if (wid == 0) { pt0 = 0;   ptot = 17; pwarm = 0; gt0 = 0;  }
        if (wid == 1) { pt0 = 256; ptot = 17; pwarm = 9; gt0 = 8;  }
        if (wid == 2) { pt0 = 512; ptot = 16; pwarm = 9; gt0 = 16; }
        const float* xrow = x + (size_t)(n0 + lane) * T_LEN + pt0;

        double s_m = 0.0, s_s = 0.0;
        unsigned b0 = 0, b1 = 0, b2 = 0, b3 = 0;   // bit FIFO: tiles li-4..li-1
        float cur[32], nxt[32];
        #pragma unroll
        for (int j = 0; j < 8; ++j) {
            float4 t = *(const float4*)(xrow + j * 4);
            cur[4*j+0]=t.x; cur[4*j+1]=t.y; cur[4*j+2]=t.z; cur[4*j+3]=t.w;
        }

        for (int li = 0; li < ptot; ++li) {
            if (li + 1 < ptot) {               // prefetch next tile
                #pragma unroll
                for (int j = 0; j < 8; ++j) {
                    float4 t = *(const float4*)(xrow + (li+1)*32 + j*4);
                    nxt[4*j+0]=t.x; nxt[4*j+1]=t.y; nxt[4*j+2]=t.z; nxt[4*j+3]=t.w;
                }
            }
            // step t=pt0+li*32+k needs x[t-100]: k<4 -> tile li-4 bit 28+k,
            // k>=4 -> tile li-3 bit k-4.
            const unsigned wmask = (b0 >> 28) | (b1 << 4);
            unsigned bcur = 0;
            const int gt = gt0 + li;
            if (li >= pwarm) {
                while (gt - __hip_atomic_load(consp, __ATOMIC_ACQUIRE,
                                              __HIP_MEMORY_SCOPE_WORKGROUP) >= VMRING)
                    __builtin_amdgcn_s_sleep(1);
                double* vrow = (double*)lds
                             + (size_t)(gt % VMRING) * VSLOTD + (size_t)lane * VROWW;
                #pragma unroll
                for (int k = 0; k < 32; ++k) {
                    const float  xf = cur[k];
                    const double xc = (double)xf;
                    const unsigned bd = (wmask >> k) & 1u;
                    s_m = fma(a_m, s_m, xc - (bd ? am100 : 0.0));
                    s_s = fma(a_s, s_s, xc - (bd ? as100 : 0.0));
                    vrow[k ^ vsw] = s_m - s_s;        // swizzled store
                    if (xf != 0.0f) bcur |= (1u << k);
                }
                __hip_atomic_store(&flags[gt], 1, __ATOMIC_RELEASE,
                                   __HIP_MEMORY_SCOPE_WORKGROUP);
            } else {                            // warmup tile
                #pragma unroll
                for (int k = 0; k < 32; ++k) {
                    const float  xf = cur[k];
                    const double xc = (double)xf;
                    const unsigned bd = (wmask >> k) & 1u;
                    s_m = fma(a_m, s_m, xc - (bd ? am100 : 0.0));
                    s_s = fma(a_s, s_s, xc - (bd ? as100 : 0.0));
                    if (xf != 0.0f) bcur |= (1u << k);
                }
            }
            b0 = b1; b1 = b2; b2 = b3; b3 = bcur;
            #pragma unroll
            for (int i2 = 0; i2 < 32; ++i2) cur[i2] = nxt[i2];
        }
    } else if (wid == 3) {
        // ============== consumer (gold r-scan, reg double-buffer) ==============
        const double alpha = (double)rk[1] / (double)rk[0];
        double r = 0.0;
        double vmA[32], vmB[32];

#define CPREF(VM, GT) do {                                                  \
            while (!__hip_atomic_load(&flags[(GT)], __ATOMIC_ACQUIRE,       \
                                      __HIP_MEMORY_SCOPE_WORKGROUP))        \
                __builtin_amdgcn_s_sleep(1);                                \
            const double* vrow_ = (const double*)lds                        \
                + (size_t)((GT) % VMRING) * VSLOTD + (size_t)lane * VROWW;  \
            _Pragma("unroll")                                               \
            for (int k_ = 0; k_ < 32; ++k_) (VM)[k_] = vrow_[k_ ^ vsw];     \
        } while (0)

#define CSCAN(VM, GT) do {                                                  \
            while (__hip_atomic_load(wprog, __ATOMIC_ACQUIRE,               \
                       __HIP_MEMORY_SCOPE_WORKGROUP) < (GT) - 1)            \
                __builtin_amdgcn_s_sleep(1);                                \
            float* orow_ = ob + ((GT) & 1) * OBSLOTW + lane * OROWW;        \
            _Pragma("unroll")                                               \
            for (int k_ = 0; k_ < 32; ++k_) {       /* gold op order */     \
                double v_ = (VM)[k_] - r;                                   \
                double n_ = fmax(floor(v_), 0.0);                           \
                r = (r + n_) * alpha;                                       \
                orow_[k_] = (float)n_;                                      \
            }                                                               \
            __hip_atomic_store(consp, (GT) + 1, __ATOMIC_RELEASE,           \
                               __HIP_MEMORY_SCOPE_WORKGROUP);               \
        } while (0)

        CPREF(vmA, 0);
        for (int gt = 0; gt < NT; gt += 2) {
            if (gt + 1 < NT) CPREF(vmB, gt + 1);   // reads land under scan
            CSCAN(vmA, gt);
            if (gt + 2 < NT) CPREF(vmA, gt + 2);
            CSCAN(vmB, gt + 1);
        }
#undef CPREF
#undef CSCAN
    } else {
        // ===================== writer (coalesced flush) =====================
        for (int gt = 0; gt < NT; ++gt) {
            while (__hip_atomic_load(consp, __ATOMIC_ACQUIRE,
                                     __HIP_MEMORY_SCOPE_WORKGROUP) < gt + 1)
                __builtin_amdgcn_s_sleep(1);
            const float* obs = ob + (gt & 1) * OBSLOTW;
            #pragma unroll
            for (int j = 0; j < 8; ++j) {
                const int nn = rowq + 8 * j;
                float4 t = *(const float4*)(obs + nn * OROWW + colq * 4);
                *(float4*)(og + (size_t)nn * T_LEN + gt * 32 + colq * 4) = t;
            }
            __hip_atomic_store(wprog, gt + 1, __ATOMIC_RELEASE,
                               __HIP_MEMORY_SCOPE_WORKGROUP);
        }
    }
}

extern "C" void kernel_launch(void* const* d_in, const int* in_sizes, int n_in,
                              void* d_out, int out_size, void* d_ws, size_t ws_size,
                              hipStream_t stream)
{
    const float* x  = (const float*)d_in[0];   // binary_input (1,32,1024,1024)
    const float* rk = (const float*)d_in[2];   // ref_kernel (100,)
    float* out = (float*)d_out;                // spikes (32,1024,1024) f32

    const int neurons = in_sizes[0] / T_LEN;   // 32768

    const double a_m   = std::exp(-0.1);       // exp(-dt/tau_mem)
    const double a_s   = std::exp(-0.2);       // exp(-dt/tau_syn)
    const double am100 = std::exp(-10.0);
    const double as100 = std::exp(-20.0);

    dim3 grid(neurons / 64), block(320);
    hipLaunchKernelGGL(spiking_fwd, grid, block, 0, stream,
                       x, rk, out, a_m, a_s, am100, as100);
}

// Round 11
// 72.267 us; speedup vs baseline: 4.2496x; 1.2336x over previous
//
#include <hip/hip_runtime.h>
#include <cmath>

// SpikingLayer forward — dynamic producer/consumer, register-light pipelined
// consumer with direct global scatter stores.
//
// vmem[t] = sum_{k<100} (am^k - as^k) x[t-k] (exact truncated-FIR via dual
// 1st-order f64 recurrences; time-chunked, 288-step zero-history warmup =
// mathematically exact after 100 steps). The nonlinear refractory scan is
// NEVER chunked: wave 3 runs it sequentially per neuron in f64, gold op
// order (rounds 5/8/9/10 all absmax 0.0 with this math).
//
// Base = round 5 (69us). Round-10's lesson: 32-deep register double-buffer
// spilled (VGPR=76 < declared arrays) -> scratch round-trips; writer-wave
// handshake added poll latency. Round-11 deltas:
//  1. Consumer pipelines vm reads in chunks of 8 with TWO 8-double arrays
//     (32 VGPRs, fully static unroll): chunk h+1's ds_reads fly while chunk
//     h scans. No spill.
//  2. No ob staging / no flush: consumer packs 4 steps into a float4 and
//     stores DIRECTLY to global (per-lane, fire-and-forget). Removes ~400
//     cyc/tile of LDS round-trip from the serial path; scatter writes merge
//     in L2 (HBM util is 11% — traffic is free, latency is not).
//  3. Producer = round-5 gold math + round-9-proven bank swizzle. RING=4.

#define T_LEN   1024
#define NT      32
#define RING    4
#define VROWW   33                        // doubles per vmem row (264 B)
#define VSLOTD  (64 * VROWW)              // 2112 doubles per ring slot
#define LDS_FLG (RING * VSLOTD * 8)       // 67584
#define LDS_TOT (LDS_FLG + 33 * 4)        // 67716 B

__global__ __launch_bounds__(256, 2)
void spiking_fwd(const float* __restrict__ x, const float* __restrict__ rk,
                 float* __restrict__ out,
                 double a_m, double a_s, double am100, double as100)
{
    __shared__ __align__(16) unsigned char lds[LDS_TOT];
    int* const flags = (int*)(lds + LDS_FLG);   // [0..31] tile-ready
    int* const consp = flags + NT;              // tiles consumed

    const int tid = threadIdx.x, wid = tid >> 6, lane = tid & 63;
    const int n0 = blockIdx.x * 64;
    const unsigned vsw = (lane >> 4) & 3;       // vmem bank swizzle (r9-proven)

    if (tid <= NT) flags[tid] = 0;
    __syncthreads();

    if (wid < 3) {
        // ===================== producer (gold math) =====================
        // chunks [0,544) [544,800) [800,1024), warmup 288 for P1/P2
        int pwarm = 0, ptot = 0, pt0 = 0, gt0 = 0;
        if (wid == 0) { pt0 = 0;   ptot = 17; pwarm = 0; gt0 = 0;  }
        if (wid == 1) { pt0 = 256; ptot = 17; pwarm = 9; gt0 = 8;  }
        if (wid == 2) { pt0 = 512; ptot = 16; pwarm = 9; gt0 = 16; }
        const float* xrow = x + (size_t)(n0 + lane) * T_LEN + pt0;

        double s_m = 0.0, s_s = 0.0;
        unsigned b0 = 0, b1 = 0, b2 = 0, b3 = 0;   // bit FIFO: tiles li-4..li-1
        float cur[32], nxt[32];
        #pragma unroll
        for (int j = 0; j < 8; ++j) {
            float4 t = *(const float4*)(xrow + j * 4);
            cur[4*j+0]=t.x; cur[4*j+1]=t.y; cur[4*j+2]=t.z; cur[4*j+3]=t.w;
        }

        for (int li = 0; li < ptot; ++li) {
            if (li + 1 < ptot) {               // prefetch next tile
                #pragma unroll
                for (int j = 0; j < 8; ++j) {
                    float4 t = *(const float4*)(xrow + (li+1)*32 + j*4);
                    nxt[4*j+0]=t.x; nxt[4*j+1]=t.y; nxt[4*j+2]=t.z; nxt[4*j+3]=t.w;
                }
            }
            // step t=pt0+li*32+k needs x[t-100]: k<4 -> tile li-4 bit 28+k,
            // k>=4 -> tile li-3 bit k-4.
            const unsigned wmask = (b0 >> 28) | (b1 << 4);
            unsigned bcur = 0;
            const int gt = gt0 + li;
            if (li >= pwarm) {
                while (gt - __hip_atomic_load(consp, __ATOMIC_ACQUIRE,
                                              __HIP_MEMORY_SCOPE_WORKGROUP) >= RING)
                    __builtin_amdgcn_s_sleep(1);
                double* vrow = (double*)lds
                             + (size_t)(gt & (RING-1)) * VSLOTD + (size_t)lane * VROWW;
                #pragma unroll
                for (int k = 0; k < 32; ++k) {
                    const float  xf = cur[k];
                    const double xc = (double)xf;
                    const unsigned bd = (wmask >> k) & 1u;
                    s_m = fma(a_m, s_m, xc - (bd ? am100 : 0.0));
                    s_s = fma(a_s, s_s, xc - (bd ? as100 : 0.0));
                    vrow[k ^ vsw] = s_m - s_s;        // swizzled store
                    if (xf != 0.0f) bcur |= (1u << k);
                }
                __hip_atomic_store(&flags[gt], 1, __ATOMIC_RELEASE,
                                   __HIP_MEMORY_SCOPE_WORKGROUP);
            } else {                            // warmup tile
                #pragma unroll
                for (int k = 0; k < 32; ++k) {
                    const float  xf = cur[k];
                    const double xc = (double)xf;
                    const unsigned bd = (wmask >> k) & 1u;
                    s_m = fma(a_m, s_m, xc - (bd ? am100 : 0.0));
                    s_s = fma(a_s, s_s, xc - (bd ? as100 : 0.0));
                    if (xf != 0.0f) bcur |= (1u << k);
                }
            }
            b0 = b1; b1 = b2; b2 = b3; b3 = bcur;
            #pragma unroll
            for (int i2 = 0; i2 < 32; ++i2) cur[i2] = nxt[i2];
        }
    } else {
        // ====== consumer: gold r-scan, 8-chunk pipeline, direct stores ======
        const double alpha = (double)rk[1] / (double)rk[0];
        double r = 0.0;
        float* const gdst0 = out + (size_t)(n0 + lane) * T_LEN;

#define STEP1(VMV, OO) do {                                   \
            double v_ = (VMV) - r;                            \
            double n_ = fmax(floor(v_), 0.0);                 \
            r = (r + n_) * alpha;                             \
            OO = (float)n_;                                   \
        } while (0)

#define PREF(VM, H) do {                                      \
            _Pragma("unroll")                                 \
            for (int k2 = 0; k2 < 8; ++k2)                    \
                (VM)[k2] = vrow[((H)*8 + k2) ^ vsw];          \
        } while (0)

#define SCANCH(VM, H) do {                                    \
            float4 o0, o1;                                    \
            STEP1((VM)[0], o0.x); STEP1((VM)[1], o0.y);       \
            STEP1((VM)[2], o0.z); STEP1((VM)[3], o0.w);       \
            STEP1((VM)[4], o1.x); STEP1((VM)[5], o1.y);       \
            STEP1((VM)[6], o1.z); STEP1((VM)[7], o1.w);       \
            *(float4*)(gdst + (H)*8)     = o0;                \
            *(float4*)(gdst + (H)*8 + 4) = o1;                \
        } while (0)

        for (int gt = 0; gt < NT; ++gt) {
            while (!__hip_atomic_load(&flags[gt], __ATOMIC_ACQUIRE,
                                      __HIP_MEMORY_SCOPE_WORKGROUP))
                __builtin_amdgcn_s_sleep(1);
            const double* vrow = (const double*)lds
                               + (size_t)(gt & (RING-1)) * VSLOTD
                               + (size_t)lane * VROWW;
            float* gdst = gdst0 + gt * 32;

            double vA[8], vB[8];
            PREF(vA, 0);
            PREF(vB, 1);         // in flight while chunk 0 scans
            SCANCH(vA, 0);
            PREF(vA, 2);         // in flight while chunk 1 scans
            SCANCH(vB, 1);
            PREF(vB, 3);         // in flight while chunk 2 scans
            SCANCH(vA, 2);
            SCANCH(vB, 3);

            __hip_atomic_store(consp, gt + 1, __ATOMIC_RELEASE,
                               __HIP_MEMORY_SCOPE_WORKGROUP);
        }
#undef SCANCH
#undef PREF
#undef STEP1
    }
}

extern "C" void kernel_launch(void* const* d_in, const int* in_sizes, int n_in,
                              void* d_out, int out_size, void* d_ws, size_t ws_size,
                              hipStream_t stream)
{
    const float* x  = (const float*)d_in[0];   // binary_input (1,32,1024,1024)
    const float* rk = (const float*)d_in[2];   // ref_kernel (100,)
    float* out = (float*)d_out;                // spikes (32,1024,1024) f32

    const int neurons = in_sizes[0] / T_LEN;   // 32768

    const double a_m   = std::exp(-0.1);       // exp(-dt/tau_mem)
    const double a_s   = std::exp(-0.2);       // exp(-dt/tau_syn)
    const double am100 = std::exp(-10.0);
    const double as100 = std::exp(-20.0);

    dim3 grid(neurons / 64), block(256);
    hipLaunchKernelGGL(spiking_fwd, grid, block, 0, stream,
                       x, rk, out, a_m, a_s, am100, as100);
}